// Round 12
// baseline (315.763 us; speedup 1.0000x reference)
//
#include <hip/hip_runtime.h>

#define NFEAT 128
#define HID 16
#define NCLS 40
#define BSHIFT 7                 // 128 nodes per bucket
#define BNODES 128
#define CAP 2560                 // slab capacity per bucket (Poisson mean ~2046, 11 sigma)
#define NBUCK_MAX 800            // >= ceil(100000/128)=782
#define NNODE_MAX 102400         // deg/cursor/nodebase arrays (>=100000)
#define BIN_CHUNK 4096           // edges per count/scatter block (16 per thread)
#define ZPAD 41

typedef __attribute__((ext_vector_type(8))) short short8;   // 8 x bf16 (4 VGPRs)
typedef __attribute__((ext_vector_type(4))) float f32x4;

__device__ __forceinline__ unsigned bf16_rne(float f) {
    unsigned u = __float_as_uint(f);
    return (u + 0x7FFFu + ((u >> 16) & 1u)) >> 16;
}
__device__ __forceinline__ float bf_lo(unsigned u) { return __uint_as_float(u << 16); }
__device__ __forceinline__ float bf_hi(unsigned u) { return __uint_as_float(u & 0xFFFF0000u); }

// ---------- zero deg + cursor ----------
__global__ __launch_bounds__(256) void zero_kernel(int* __restrict__ p, int m)
{
    int i = blockIdx.x * 256 + threadIdx.x;
    if (i < m) p[i] = 0;
}

// ---------- fused: degree count (global atomics) + gemm1 (x@W1 via MFMA) ----
__global__ __launch_bounds__(256) void count_gemm_kernel(const int* __restrict__ dst,
                                                         int* __restrict__ deg,
                                                         int E, int nbin,
                                                         const float* __restrict__ x,
                                                         const float* __restrict__ W1,
                                                         unsigned short* __restrict__ h1b,
                                                         int n)
{
    int tid = threadIdx.x;
    if (blockIdx.x < nbin) {
        // ----- count path: histogram node in-degrees -----
        int base = blockIdx.x * BIN_CHUNK + tid;
        #pragma unroll
        for (int k = 0; k < 16; ++k) {
            int e = base + k * 256;
            if (e < E) atomicAdd(&deg[dst[e]], 1);
        }
    } else {
        // ----- gemm1 path: 64 rows per block via MFMA -----
        int wave = tid >> 6, lane = tid & 63;
        int m = lane & 15, q = lane >> 4;
        int base = (blockIdx.x - nbin) * 64 + wave * 16;

        short8 bfrag[4];
        #pragma unroll
        for (int kc = 0; kc < 4; ++kc) {
            #pragma unroll
            for (int j = 0; j < 8; ++j)
                bfrag[kc][j] = (short)bf16_rne(W1[(kc * 32 + q * 8 + j) * HID + m]);
        }

        int rowa = base + m; if (rowa > n - 1) rowa = n - 1;
        const float* xr = x + (size_t)rowa * NFEAT;
        f32x4 acc = {0.f, 0.f, 0.f, 0.f};
        #pragma unroll
        for (int kc = 0; kc < 4; ++kc) {
            float4 a0 = *(const float4*)(xr + kc * 32 + q * 8);
            float4 a1 = *(const float4*)(xr + kc * 32 + q * 8 + 4);
            short8 af;
            af[0] = (short)bf16_rne(a0.x); af[1] = (short)bf16_rne(a0.y);
            af[2] = (short)bf16_rne(a0.z); af[3] = (short)bf16_rne(a0.w);
            af[4] = (short)bf16_rne(a1.x); af[5] = (short)bf16_rne(a1.y);
            af[6] = (short)bf16_rne(a1.z); af[7] = (short)bf16_rne(a1.w);
            acc = __builtin_amdgcn_mfma_f32_16x16x32_bf16(af, bfrag[kc], acc, 0, 0, 0);
        }
        #pragma unroll
        for (int reg = 0; reg < 4; ++reg) {
            int rowd = base + q * 4 + reg;
            if (rowd < n)
                h1b[(size_t)rowd * HID + m] = (unsigned short)bf16_rne(acc[reg]);
        }
    }
}

// ---------- per-bucket exclusive scan of degrees -> absolute node bases ------
// one wave per bucket; lane l handles nodes 2l, 2l+1 of the bucket.
__global__ __launch_bounds__(64) void scan_kernel(const int* __restrict__ deg,
                                                  int* __restrict__ nodebase,
                                                  int n)
{
    int b = blockIdx.x, l = threadIdx.x;
    int n0 = (b << BSHIFT) + 2 * l;
    int d0 = (n0     < n) ? deg[n0]     : 0;
    int d1 = (n0 + 1 < n) ? deg[n0 + 1] : 0;
    int s = d0 + d1;
    int incl = s;
    #pragma unroll
    for (int off = 1; off < 64; off <<= 1) {
        int t = __shfl_up(incl, off);
        if (l >= off) incl += t;
    }
    int excl = incl - s;
    int e0 = excl;      if (e0 > CAP) e0 = CAP;   // overflow clamp (11-sigma)
    int e1 = excl + d0; if (e1 > CAP) e1 = CAP;
    int base = b * CAP;
    if (n0     < n) nodebase[n0]     = base + e0;
    if (n0 + 1 < n) nodebase[n0 + 1] = base + e1;
}

// ---------- scatter edges into dst-sorted CSR slab ----------
// slab[k] = { src, bits(weight) } for k in [nodebase[d], nodebase[d]+deg[d])
__global__ __launch_bounds__(256) void scatter_kernel(const int* __restrict__ src,
                                                      const int* __restrict__ dst,
                                                      const float* __restrict__ ew,
                                                      const int* __restrict__ nodebase,
                                                      int* __restrict__ cursor,
                                                      int2* __restrict__ slab, int E)
{
    int base = blockIdx.x * BIN_CHUNK + threadIdx.x;
    #pragma unroll
    for (int k = 0; k < 16; ++k) {
        int e = base + k * 256;
        if (e < E) {
            int d = dst[e];
            int pos = nodebase[d] + atomicAdd(&cursor[d], 1);
            int bend = ((d >> BSHIFT) + 1) * CAP;
            if (pos < bend)                        // overflow guard
                slab[pos] = make_int2(src[e], __float_as_int(ew[e]));
        }
    }
}

// ---------- gather layer 1: CSR pull, fp32 register accumulation ----------
// thread = (node, half): lanes 2i/2i+1 share a node -> edge loads pair-merge,
// the two 16B hq halves hit one 32B segment. No LDS, no atomics.
__global__ __launch_bounds__(256) void gather1_kernel(const uint4* __restrict__ hq,
                                                      const int* __restrict__ nodebase,
                                                      const int* __restrict__ deg,
                                                      const int2* __restrict__ slab,
                                                      uint4* __restrict__ outb, int n)
{
    int gid = blockIdx.x * 256 + threadIdx.x;
    int node = gid >> 1, p = gid & 1;
    if (node >= n) return;

    int beg = nodebase[node];
    int dg  = deg[node];
    int bend = ((node >> BSHIFT) + 1) * CAP;
    int end = beg + dg; if (end > bend) end = bend;

    uint4 own = hq[(size_t)node * 2 + p];          // self loop (weight 1)
    float a0 = bf_lo(own.x), a1 = bf_hi(own.x);
    float a2 = bf_lo(own.y), a3 = bf_hi(own.y);
    float a4 = bf_lo(own.z), a5 = bf_hi(own.z);
    float a6 = bf_lo(own.w), a7 = bf_hi(own.w);

    int k = beg;
    int2 e0; uint4 q0;
    if (k < end) { e0 = slab[k]; q0 = hq[(size_t)e0.x * 2 + p]; }
    while (k < end) {
        int kn = k + 1;
        int2 e1; uint4 q1;
        if (kn < end) { e1 = slab[kn]; q1 = hq[(size_t)e1.x * 2 + p]; }
        float w = __int_as_float(e0.y);
        a0 += w * bf_lo(q0.x); a1 += w * bf_hi(q0.x);
        a2 += w * bf_lo(q0.y); a3 += w * bf_hi(q0.y);
        a4 += w * bf_lo(q0.z); a5 += w * bf_hi(q0.z);
        a6 += w * bf_lo(q0.w); a7 += w * bf_hi(q0.w);
        e0 = e1; q0 = q1; k = kn;
    }

    uint4 o;
    o.x = bf16_rne(a0) | (bf16_rne(a1) << 16);
    o.y = bf16_rne(a2) | (bf16_rne(a3) << 16);
    o.z = bf16_rne(a4) | (bf16_rne(a5) << 16);
    o.w = bf16_rne(a6) | (bf16_rne(a7) << 16);
    outb[(size_t)node * 2 + p] = o;
}

// ---------- gather layer 2: CSR pull + W2 projection + log_softmax ----------
// block = 256 threads = 128 nodes (2 half-threads per node). Each half-thread
// accumulates 8 features then a partial z[40]; halves combine via LDS.
__global__ __launch_bounds__(256) void gather2_lsm_kernel(const uint4* __restrict__ hq,
                                                          const int* __restrict__ nodebase,
                                                          const int* __restrict__ deg,
                                                          const int2* __restrict__ slab,
                                                          const float* __restrict__ W2,
                                                          float* __restrict__ out, int n)
{
    __shared__ float w2s[HID * NCLS];       // 2.56 KB
    __shared__ float zbuf[BNODES * ZPAD];   // 21 KB
    int tid = threadIdx.x;
    for (int i = tid; i < HID * NCLS; i += 256) w2s[i] = W2[i];

    int node0 = blockIdx.x << BSHIFT;
    int dl = tid >> 1, p = tid & 1;
    int node = node0 + dl;
    bool alive = node < n;

    float a0 = 0.f, a1 = 0.f, a2 = 0.f, a3 = 0.f,
          a4 = 0.f, a5 = 0.f, a6 = 0.f, a7 = 0.f;
    if (alive) {
        int beg = nodebase[node];
        int dg  = deg[node];
        int bend = ((node >> BSHIFT) + 1) * CAP;
        int end = beg + dg; if (end > bend) end = bend;

        uint4 own = hq[(size_t)node * 2 + p];      // self loop
        a0 = bf_lo(own.x); a1 = bf_hi(own.x);
        a2 = bf_lo(own.y); a3 = bf_hi(own.y);
        a4 = bf_lo(own.z); a5 = bf_hi(own.z);
        a6 = bf_lo(own.w); a7 = bf_hi(own.w);

        int k = beg;
        int2 e0; uint4 q0;
        if (k < end) { e0 = slab[k]; q0 = hq[(size_t)e0.x * 2 + p]; }
        while (k < end) {
            int kn = k + 1;
            int2 e1; uint4 q1;
            if (kn < end) { e1 = slab[kn]; q1 = hq[(size_t)e1.x * 2 + p]; }
            float w = __int_as_float(e0.y);
            a0 += w * bf_lo(q0.x); a1 += w * bf_hi(q0.x);
            a2 += w * bf_lo(q0.y); a3 += w * bf_hi(q0.y);
            a4 += w * bf_lo(q0.z); a5 += w * bf_hi(q0.z);
            a6 += w * bf_lo(q0.w); a7 += w * bf_hi(q0.w);
            e0 = e1; q0 = q1; k = kn;
        }
    }
    __syncthreads();                       // w2s ready; zbuf safe to write

    // partial z over this half's 8 features
    float z[NCLS];
    #pragma unroll
    for (int j = 0; j < NCLS; ++j) z[j] = 0.f;
    if (alive) {
        float r[8] = {a0, a1, a2, a3, a4, a5, a6, a7};
        #pragma unroll
        for (int f = 0; f < 8; ++f) {
            float rf = r[f];
            const float* wr = &w2s[(p * 8 + f) * NCLS];
            #pragma unroll
            for (int j = 0; j < NCLS; ++j) z[j] += rf * wr[j];
        }
    }

    if (alive && p == 0) {
        #pragma unroll
        for (int j = 0; j < NCLS; ++j) zbuf[dl * ZPAD + j] = z[j];
    }
    __syncthreads();
    if (alive && p == 1) {
        float zt[NCLS];
        #pragma unroll
        for (int j = 0; j < NCLS; ++j) zt[j] = z[j] + zbuf[dl * ZPAD + j];
        float m = zt[0];
        #pragma unroll
        for (int j = 1; j < NCLS; ++j) m = fmaxf(m, zt[j]);
        float ssum = 0.f;
        #pragma unroll
        for (int j = 0; j < NCLS; ++j) ssum += __expf(zt[j] - m);
        float l = m + __logf(ssum);
        #pragma unroll
        for (int j = 0; j < NCLS; ++j) zbuf[dl * ZPAD + j] = zt[j] - l;
    }
    __syncthreads();

    for (int i = tid; i < BNODES * NCLS; i += 256) {
        int nl = i / NCLS, j = i - nl * NCLS;
        if (node0 + nl < n)
            out[(size_t)node0 * NCLS + i] = zbuf[nl * ZPAD + j];
    }
}

extern "C" void kernel_launch(void* const* d_in, const int* in_sizes, int n_in,
                              void* d_out, int out_size, void* d_ws, size_t ws_size,
                              hipStream_t stream)
{
    const float* x  = (const float*)d_in[0];
    const float* ew = (const float*)d_in[1];
    const float* W1 = (const float*)d_in[2];
    const float* W2 = (const float*)d_in[3];
    const int*   ei = (const int*)d_in[4];

    int n = in_sizes[0] / NFEAT;     // 100000
    int E = in_sizes[1];             // 1600000
    const int* src = ei;
    const int* dst = ei + E;
    float* out = (float*)d_out;

    int nbuck = (n + BNODES - 1) >> BSHIFT;           // 782
    int nbin  = (E + BIN_CHUNK - 1) / BIN_CHUNK;      // 391
    int ngemm = (n + 63) / 64;                        // 1563

    // ---- workspace layout ----
    char* w = (char*)d_ws;
    int* deg      = (int*)w; w += NNODE_MAX * 4;      // 400 KB
    int* cursor   = (int*)w; w += NNODE_MAX * 4;      // 400 KB
    int* nodebase = (int*)w; w += NNODE_MAX * 4;      // 400 KB
    w = (char*)(((size_t)w + 15) & ~(size_t)15);
    int2* slab    = (int2*)w; w += (size_t)NBUCK_MAX * CAP * 8;          // 16 MB
    unsigned short* h1b = (unsigned short*)w; w += (size_t)n * HID * 2;  // 3.2 MB
    unsigned short* h2b = (unsigned short*)w; w += (size_t)n * HID * 2;  // 3.2 MB

    zero_kernel<<<(2 * NNODE_MAX + 255) / 256, 256, 0, stream>>>(deg, 2 * NNODE_MAX);
    count_gemm_kernel<<<nbin + ngemm, 256, 0, stream>>>(dst, deg, E, nbin,
                                                        x, W1, h1b, n);
    scan_kernel<<<nbuck, 64, 0, stream>>>(deg, nodebase, n);
    scatter_kernel<<<nbin, 256, 0, stream>>>(src, dst, ew, nodebase, cursor, slab, E);
    gather1_kernel<<<(2 * n + 255) / 256, 256, 0, stream>>>((const uint4*)h1b,
                                                            nodebase, deg, slab,
                                                            (uint4*)h2b, n);
    gather2_lsm_kernel<<<nbuck, 256, 0, stream>>>((const uint4*)h2b, nodebase, deg,
                                                  slab, W2, out, n);
}

// Round 13
// 172.016 us; speedup vs baseline: 1.8357x; 1.8357x over previous
//
#include <hip/hip_runtime.h>

#define NFEAT 128
#define HID 16
#define NCLS 40
#define BSHIFT 7                 // 128 nodes per bucket
#define BNODES 128
#define CAP 2560                 // slab capacity per bucket (Poisson mean ~2046, 11 sigma)
#define NBUCK_MAX 800            // >= ceil(100000/128)=782
#define BIN_CHUNK 4096           // edges per bin block (16 per thread)
#define APAD 17                  // accum stride: 16 feats + 1 pad
#define ZPAD 41

#define SCALE1 262144.0f         // 2^18 — layer-1 message quantization
#define SCALE2 65536.0f          // 2^16 — layer-2 message quantization

typedef __attribute__((ext_vector_type(8))) short short8;   // 8 x bf16 (4 VGPRs)
typedef __attribute__((ext_vector_type(4))) float f32x4;

__device__ __forceinline__ unsigned bf16_rne(float f) {
    unsigned u = __float_as_uint(f);
    return (u + 0x7FFFu + ((u >> 16) & 1u)) >> 16;
}
__device__ __forceinline__ float bf_lo(unsigned u) { return __uint_as_float(u << 16); }
__device__ __forceinline__ float bf_hi(unsigned u) { return __uint_as_float(u & 0xFFFF0000u); }

// ---------- cursor init ----------
__global__ __launch_bounds__(256) void zero_kernel(int* __restrict__ p, int m)
{
    int i = blockIdx.x * 256 + threadIdx.x;
    if (i < m) p[i] = 0;
}

// ---------- fused bin + gemm1 (proven 169-path component, unchanged) ----------
__global__ __launch_bounds__(256) void bin_gemm_kernel(const int* __restrict__ src,
                                                       const int* __restrict__ dst,
                                                       const float* __restrict__ ew,
                                                       int* __restrict__ cursor,
                                                       int2* __restrict__ slab,
                                                       int E, int nbuck, int nbin,
                                                       const float* __restrict__ x,
                                                       const float* __restrict__ W1,
                                                       unsigned short* __restrict__ h1b,
                                                       int n)
{
    __shared__ int hist[NBUCK_MAX];      // 3.2 KB (bin path only)
    __shared__ int runbase[NBUCK_MAX];   // 3.2 KB (bin path only)
    int tid = threadIdx.x;

    if (blockIdx.x < nbin) {
        // ================= bin path (LDS histogram — global atomics per
        // (block,bucket) only; round-12 proved per-edge global atomics cost 6x)
        for (int i = tid; i < NBUCK_MAX; i += 256) hist[i] = 0;
        __syncthreads();

        int base = blockIdx.x * BIN_CHUNK;
        int myd[16], mys[16], myw[16];
        #pragma unroll
        for (int k = 0; k < 16; ++k) {
            int e = base + k * 256 + tid;
            if (e < E) {
                myd[k] = dst[e];
                mys[k] = src[e];
                myw[k] = __float_as_int(ew[e]);
                atomicAdd(&hist[myd[k] >> BSHIFT], 1);       // native ds_add
            } else myd[k] = -1;
        }
        __syncthreads();
        for (int i = tid; i < nbuck; i += 256) {
            int c = hist[i];
            runbase[i] = c ? (i * CAP + atomicAdd(&cursor[i], c)) : 0;
            hist[i] = 0;                                     // reuse as intra-block cursor
        }
        __syncthreads();
        #pragma unroll
        for (int k = 0; k < 16; ++k) {
            int d = myd[k];
            if (d >= 0) {
                int b = d >> BSHIFT;
                int pos = runbase[b] + atomicAdd(&hist[b], 1);
                if (pos < (b + 1) * CAP)                     // overflow guard
                    slab[pos] = make_int2(mys[k] | ((d & (BNODES - 1)) << 20), myw[k]);
            }
        }
    } else {
        // ================= gemm1 path =================
        int wave = tid >> 6, lane = tid & 63;
        int m = lane & 15, q = lane >> 4;
        int base = (blockIdx.x - nbin) * 64 + wave * 16;

        short8 bfrag[4];
        #pragma unroll
        for (int kc = 0; kc < 4; ++kc) {
            #pragma unroll
            for (int j = 0; j < 8; ++j)
                bfrag[kc][j] = (short)bf16_rne(W1[(kc * 32 + q * 8 + j) * HID + m]);
        }

        int rowa = base + m; if (rowa > n - 1) rowa = n - 1;
        const float* xr = x + (size_t)rowa * NFEAT;
        f32x4 acc = {0.f, 0.f, 0.f, 0.f};
        #pragma unroll
        for (int kc = 0; kc < 4; ++kc) {
            float4 a0 = *(const float4*)(xr + kc * 32 + q * 8);
            float4 a1 = *(const float4*)(xr + kc * 32 + q * 8 + 4);
            short8 af;
            af[0] = (short)bf16_rne(a0.x); af[1] = (short)bf16_rne(a0.y);
            af[2] = (short)bf16_rne(a0.z); af[3] = (short)bf16_rne(a0.w);
            af[4] = (short)bf16_rne(a1.x); af[5] = (short)bf16_rne(a1.y);
            af[6] = (short)bf16_rne(a1.z); af[7] = (short)bf16_rne(a1.w);
            acc = __builtin_amdgcn_mfma_f32_16x16x32_bf16(af, bfrag[kc], acc, 0, 0, 0);
        }
        #pragma unroll
        for (int reg = 0; reg < 4; ++reg) {
            int rowd = base + q * 4 + reg;
            if (rowd < n)
                h1b[(size_t)rowd * HID + m] = (unsigned short)bf16_rne(acc[reg]);
        }
    }
}

// ---------- gather layer 1: edge-merged push, 3-stage pipeline ----------
// v3: one thread = one edge (2x16B loads = one 32B line, 16 LDS atomics).
// Halves iteration count and slab/address instructions vs half-edge threads;
// (512,4): VGPR<=128 — no spill risk (round-11's (512,8) may have spilled).
__global__ __launch_bounds__(512, 4) void gather1_kernel(const uint4* __restrict__ hq,
                                                         const int* __restrict__ cursor,
                                                         const int2* __restrict__ slab,
                                                         uint4* __restrict__ outb, int n)
{
    __shared__ int accum[BNODES * APAD];   // 8.7 KB
    int tid = threadIdx.x;
    #pragma unroll
    for (int i = tid; i < BNODES * APAD; i += 512) accum[i] = 0;
    __syncthreads();

    int b = blockIdx.x;
    int beg = b * CAP;
    int cnt = cursor[b]; if (cnt > CAP) cnt = CAP;   // edges in this bucket

    int i0 = tid, i1 = tid + 512;
    int2 e0, e1; uint4 qa0, qb0;
    if (i0 < cnt) e0 = slab[beg + i0];
    if (i1 < cnt) e1 = slab[beg + i1];
    if (i0 < cnt) {
        size_t s = (size_t)(e0.x & 0xFFFFF) * 2;
        qa0 = hq[s]; qb0 = hq[s + 1];
    }

    while (i0 < cnt) {
        uint4 qa1, qb1;
        if (i1 < cnt) {
            size_t s = (size_t)(e1.x & 0xFFFFF) * 2;
            qa1 = hq[s]; qb1 = hq[s + 1];
        }
        int i2 = i1 + 512;
        int2 e2;
        if (i2 < cnt) e2 = slab[beg + i2];

        int dl = (e0.x >> 20) & (BNODES - 1);
        float wsc = __int_as_float(e0.y) * SCALE1;
        int* a = &accum[dl * APAD];
        atomicAdd(a +  0, __float2int_rn(wsc * bf_lo(qa0.x)));
        atomicAdd(a +  1, __float2int_rn(wsc * bf_hi(qa0.x)));
        atomicAdd(a +  2, __float2int_rn(wsc * bf_lo(qa0.y)));
        atomicAdd(a +  3, __float2int_rn(wsc * bf_hi(qa0.y)));
        atomicAdd(a +  4, __float2int_rn(wsc * bf_lo(qa0.z)));
        atomicAdd(a +  5, __float2int_rn(wsc * bf_hi(qa0.z)));
        atomicAdd(a +  6, __float2int_rn(wsc * bf_lo(qa0.w)));
        atomicAdd(a +  7, __float2int_rn(wsc * bf_hi(qa0.w)));
        atomicAdd(a +  8, __float2int_rn(wsc * bf_lo(qb0.x)));
        atomicAdd(a +  9, __float2int_rn(wsc * bf_hi(qb0.x)));
        atomicAdd(a + 10, __float2int_rn(wsc * bf_lo(qb0.y)));
        atomicAdd(a + 11, __float2int_rn(wsc * bf_hi(qb0.y)));
        atomicAdd(a + 12, __float2int_rn(wsc * bf_lo(qb0.z)));
        atomicAdd(a + 13, __float2int_rn(wsc * bf_hi(qb0.z)));
        atomicAdd(a + 14, __float2int_rn(wsc * bf_lo(qb0.w)));
        atomicAdd(a + 15, __float2int_rn(wsc * bf_hi(qb0.w)));

        e0 = e1; e1 = e2; qa0 = qa1; qb0 = qb1; i0 = i1; i1 = i2;
    }
    __syncthreads();

    const float inv = 1.0f / SCALE1;
    if (tid < BNODES * 2) {
        int dl = tid >> 1, p = tid & 1;
        int node = (b << BSHIFT) + dl;
        if (node < n) {
            uint4 qs = hq[(size_t)node * 2 + p];
            const int* a = &accum[dl * APAD + p * 8];
            uint4 o;
            o.x = bf16_rne((float)a[0] * inv + bf_lo(qs.x)) |
                  (bf16_rne((float)a[1] * inv + bf_hi(qs.x)) << 16);
            o.y = bf16_rne((float)a[2] * inv + bf_lo(qs.y)) |
                  (bf16_rne((float)a[3] * inv + bf_hi(qs.y)) << 16);
            o.z = bf16_rne((float)a[4] * inv + bf_lo(qs.z)) |
                  (bf16_rne((float)a[5] * inv + bf_hi(qs.z)) << 16);
            o.w = bf16_rne((float)a[6] * inv + bf_lo(qs.w)) |
                  (bf16_rne((float)a[7] * inv + bf_hi(qs.w)) << 16);
            outb[(size_t)node * 2 + p] = o;
        }
    }
}

// ---------- gather layer 2 + W2 projection + log_softmax, edge-merged ----------
__global__ __launch_bounds__(512, 4) void gather2_lsm_kernel(const uint4* __restrict__ hq,
                                                             const int* __restrict__ cursor,
                                                             const int2* __restrict__ slab,
                                                             const float* __restrict__ W2,
                                                             float* __restrict__ out, int n)
{
    __shared__ int   accum[BNODES * APAD];  // 8.7 KB
    __shared__ float w2s[HID * NCLS];       // 2.56 KB
    __shared__ float zbuf[BNODES * ZPAD];   // 21 KB
    int tid = threadIdx.x;
    #pragma unroll
    for (int i = tid; i < BNODES * APAD; i += 512) accum[i] = 0;
    for (int i = tid; i < HID * NCLS; i += 512) w2s[i] = W2[i];
    __syncthreads();

    int b = blockIdx.x;
    int beg = b * CAP;
    int cnt = cursor[b]; if (cnt > CAP) cnt = CAP;
    int node0 = b << BSHIFT;

    int i0 = tid, i1 = tid + 512;
    int2 e0, e1; uint4 qa0, qb0;
    if (i0 < cnt) e0 = slab[beg + i0];
    if (i1 < cnt) e1 = slab[beg + i1];
    if (i0 < cnt) {
        size_t s = (size_t)(e0.x & 0xFFFFF) * 2;
        qa0 = hq[s]; qb0 = hq[s + 1];
    }

    while (i0 < cnt) {
        uint4 qa1, qb1;
        if (i1 < cnt) {
            size_t s = (size_t)(e1.x & 0xFFFFF) * 2;
            qa1 = hq[s]; qb1 = hq[s + 1];
        }
        int i2 = i1 + 512;
        int2 e2;
        if (i2 < cnt) e2 = slab[beg + i2];

        int dl = (e0.x >> 20) & (BNODES - 1);
        float wsc = __int_as_float(e0.y) * SCALE2;
        int* a = &accum[dl * APAD];
        atomicAdd(a +  0, __float2int_rn(wsc * bf_lo(qa0.x)));
        atomicAdd(a +  1, __float2int_rn(wsc * bf_hi(qa0.x)));
        atomicAdd(a +  2, __float2int_rn(wsc * bf_lo(qa0.y)));
        atomicAdd(a +  3, __float2int_rn(wsc * bf_hi(qa0.y)));
        atomicAdd(a +  4, __float2int_rn(wsc * bf_lo(qa0.z)));
        atomicAdd(a +  5, __float2int_rn(wsc * bf_hi(qa0.z)));
        atomicAdd(a +  6, __float2int_rn(wsc * bf_lo(qa0.w)));
        atomicAdd(a +  7, __float2int_rn(wsc * bf_hi(qa0.w)));
        atomicAdd(a +  8, __float2int_rn(wsc * bf_lo(qb0.x)));
        atomicAdd(a +  9, __float2int_rn(wsc * bf_hi(qb0.x)));
        atomicAdd(a + 10, __float2int_rn(wsc * bf_lo(qb0.y)));
        atomicAdd(a + 11, __float2int_rn(wsc * bf_hi(qb0.y)));
        atomicAdd(a + 12, __float2int_rn(wsc * bf_lo(qb0.z)));
        atomicAdd(a + 13, __float2int_rn(wsc * bf_hi(qb0.z)));
        atomicAdd(a + 14, __float2int_rn(wsc * bf_lo(qb0.w)));
        atomicAdd(a + 15, __float2int_rn(wsc * bf_hi(qb0.w)));

        e0 = e1; e1 = e2; qa0 = qa1; qb0 = qb1; i0 = i1; i1 = i2;
    }
    __syncthreads();

    const float inv = 1.0f / SCALE2;
    if (tid < BNODES) {
        int dl = tid;
        int node = node0 + dl;
        if (node < n) {
            uint4 qa = hq[(size_t)node * 2 + 0];
            uint4 qb = hq[(size_t)node * 2 + 1];
            float r[HID];
            const int* a = &accum[dl * APAD];
            r[0]  = (float)a[ 0] * inv + bf_lo(qa.x);
            r[1]  = (float)a[ 1] * inv + bf_hi(qa.x);
            r[2]  = (float)a[ 2] * inv + bf_lo(qa.y);
            r[3]  = (float)a[ 3] * inv + bf_hi(qa.y);
            r[4]  = (float)a[ 4] * inv + bf_lo(qa.z);
            r[5]  = (float)a[ 5] * inv + bf_hi(qa.z);
            r[6]  = (float)a[ 6] * inv + bf_lo(qa.w);
            r[7]  = (float)a[ 7] * inv + bf_hi(qa.w);
            r[8]  = (float)a[ 8] * inv + bf_lo(qb.x);
            r[9]  = (float)a[ 9] * inv + bf_hi(qb.x);
            r[10] = (float)a[10] * inv + bf_lo(qb.y);
            r[11] = (float)a[11] * inv + bf_hi(qb.y);
            r[12] = (float)a[12] * inv + bf_lo(qb.z);
            r[13] = (float)a[13] * inv + bf_hi(qb.z);
            r[14] = (float)a[14] * inv + bf_lo(qb.w);
            r[15] = (float)a[15] * inv + bf_hi(qb.w);

            float z[NCLS];
            #pragma unroll
            for (int j = 0; j < NCLS; ++j) z[j] = 0.f;
            #pragma unroll
            for (int f = 0; f < HID; ++f) {
                float rf = r[f];
                #pragma unroll
                for (int j = 0; j < NCLS; ++j)
                    z[j] += rf * w2s[f * NCLS + j];   // broadcast reads
            }
            float m = z[0];
            #pragma unroll
            for (int j = 1; j < NCLS; ++j) m = fmaxf(m, z[j]);
            float ssum = 0.f;
            #pragma unroll
            for (int j = 0; j < NCLS; ++j) ssum += __expf(z[j] - m);
            float l = m + __logf(ssum);
            #pragma unroll
            for (int j = 0; j < NCLS; ++j) zbuf[dl * ZPAD + j] = z[j] - l;
        }
    }
    __syncthreads();

    for (int i = tid; i < BNODES * NCLS; i += 512) {
        int nl = i / NCLS, j = i - nl * NCLS;
        if (node0 + nl < n)
            out[(size_t)node0 * NCLS + i] = zbuf[nl * ZPAD + j];
    }
}

extern "C" void kernel_launch(void* const* d_in, const int* in_sizes, int n_in,
                              void* d_out, int out_size, void* d_ws, size_t ws_size,
                              hipStream_t stream)
{
    const float* x  = (const float*)d_in[0];
    const float* ew = (const float*)d_in[1];
    const float* W1 = (const float*)d_in[2];
    const float* W2 = (const float*)d_in[3];
    const int*   ei = (const int*)d_in[4];

    int n = in_sizes[0] / NFEAT;     // 100000
    int E = in_sizes[1];             // 1600000
    const int* src = ei;
    const int* dst = ei + E;
    float* out = (float*)d_out;

    int nbuck = (n + BNODES - 1) >> BSHIFT;           // 782
    int nbin  = (E + BIN_CHUNK - 1) / BIN_CHUNK;      // 391
    int ngemm = (n + 63) / 64;                        // 1563

    // ---- workspace layout ----
    char* w = (char*)d_ws;
    int*  cursor = (int*)w;  w += NBUCK_MAX * 4;
    w = (char*)(((size_t)w + 15) & ~(size_t)15);
    int2* slab   = (int2*)w; w += (size_t)NBUCK_MAX * CAP * 8;           // 16 MB
    unsigned short* h1b = (unsigned short*)w; w += (size_t)n * HID * 2;  // 3.2 MB bf16
    unsigned short* h2b = (unsigned short*)w; w += (size_t)n * HID * 2;  // 3.2 MB bf16

    zero_kernel<<<(NBUCK_MAX + 255) / 256, 256, 0, stream>>>(cursor, NBUCK_MAX);
    bin_gemm_kernel<<<nbin + ngemm, 256, 0, stream>>>(src, dst, ew, cursor, slab,
                                                      E, nbuck, nbin, x, W1, h1b, n);
    gather1_kernel<<<nbuck, 512, 0, stream>>>((const uint4*)h1b, cursor, slab,
                                              (uint4*)h2b, n);
    gather2_lsm_kernel<<<nbuck, 512, 0, stream>>>((const uint4*)h2b, cursor, slab,
                                                  W2, out, n);
}